// Round 1
// baseline (988.520 us; speedup 1.0000x reference)
//
#include <hip/hip_runtime.h>
#include <hip/hip_bf16.h>

// Problem constants (from reference): N=100000 nodes, E=3200000 edges,
// IN_DIM=64, HID=64, d1=65 (x augmented with tau column).
// Strategy: build CSR-by-dst once per call (deg count + scan + bucket fill),
// then each SAGE layer = one wave per node (lane = feature column):
//   gather/sum neighbor rows (coalesced 256B), mean, then
//   out = mean@Wl + h@Wr + b via shuffle-broadcast FMA against LDS-staged W.
// fc head fused into layer-2 kernel via wave reduction.

#define WAVES_PER_BLOCK 16
#define LAYER_BLOCK (WAVES_PER_BLOCK * 64)
#define LAYER_GRID 512

__global__ void k_count(const int* __restrict__ dst, int* __restrict__ deg, int E) {
    int e = blockIdx.x * 256 + threadIdx.x;
    if (e < E) atomicAdd(&deg[dst[e]], 1);
}

// exclusive scan within 256-blocks; block totals to bsum
__global__ void k_blockscan(const int* __restrict__ deg, int* __restrict__ rowptr,
                            int* __restrict__ bsum, int N) {
    __shared__ int s[256];
    int tid = threadIdx.x;
    int i = blockIdx.x * 256 + tid;
    int v = (i < N) ? deg[i] : 0;
    s[tid] = v;
    __syncthreads();
    for (int off = 1; off < 256; off <<= 1) {
        int t = (tid >= off) ? s[tid - off] : 0;
        __syncthreads();
        s[tid] += t;
        __syncthreads();
    }
    if (i < N) rowptr[i] = s[tid] - v;          // exclusive within block
    if (tid == 255) bsum[blockIdx.x] = s[255];  // block total
}

// exclusive scan of block sums (nb <= 512; nb = ceil(100000/256) = 391)
__global__ void k_scanb(int* __restrict__ bsum, int nb) {
    __shared__ int s[512];
    int tid = threadIdx.x;
    int v = (tid < nb) ? bsum[tid] : 0;
    s[tid] = v;
    __syncthreads();
    for (int off = 1; off < 512; off <<= 1) {
        int t = (tid >= off) ? s[tid - off] : 0;
        __syncthreads();
        s[tid] += t;
        __syncthreads();
    }
    if (tid < nb) bsum[tid] = s[tid] - v;  // exclusive
}

__global__ void k_finalize(int* __restrict__ rowptr, int* __restrict__ cursor,
                           const int* __restrict__ bsum, int N) {
    int i = blockIdx.x * 256 + threadIdx.x;
    if (i < N) {
        int r = rowptr[i] + bsum[blockIdx.x];
        rowptr[i] = r;
        cursor[i] = r;
    }
}

__global__ void k_fill(const int* __restrict__ src, const int* __restrict__ dst,
                       int* __restrict__ cursor, int* __restrict__ colidx, int E) {
    int e = blockIdx.x * 256 + threadIdx.x;
    if (e < E) {
        int pos = atomicAdd(&cursor[dst[e]], 1);
        colidx[pos] = src[e];
    }
}

// Layer 1: h1 = relu(mean([x|tau][nbrs]) @ W1l + [x|tau] @ W1r + b1l)
// W1l/W1r are [65,64]; row 64 is the tau row.
__global__ __launch_bounds__(LAYER_BLOCK) void k_layer1(
    const float* __restrict__ x, const float* __restrict__ tau,
    const int* __restrict__ rowptr, const int* __restrict__ deg,
    const int* __restrict__ colidx,
    const float* __restrict__ W1l, const float* __restrict__ b1l,
    const float* __restrict__ W1r, float* __restrict__ h1, int N) {
    __shared__ float sW[65 * 64 * 2];
    for (int i = threadIdx.x; i < 65 * 64 * 2; i += LAYER_BLOCK)
        sW[i] = (i < 65 * 64) ? W1l[i] : W1r[i - 65 * 64];
    __syncthreads();
    const float* sWl = sW;
    const float* sWr = sW + 65 * 64;

    int lane = threadIdx.x & 63;
    int wave = blockIdx.x * WAVES_PER_BLOCK + (threadIdx.x >> 6);
    int nwaves = gridDim.x * WAVES_PER_BLOCK;

    float bl = b1l[lane];
    float wl_tau = sWl[64 * 64 + lane];
    float wr_tau = sWr[64 * 64 + lane];

    for (int node = wave; node < N; node += nwaves) {
        int start = rowptr[node];
        int d = deg[node];
        float s0 = 0.f, s1 = 0.f, s2 = 0.f, s3 = 0.f, sumtau = 0.f;
        for (int base = 0; base < d; base += 64) {
            int n = d - base;
            if (n > 64) n = 64;
            int sidx = 0;
            if (lane < n) {
                sidx = colidx[start + base + lane];
                sumtau += tau[sidx];
            }
            int jj = 0;
            for (; jj + 4 <= n; jj += 4) {
                int a0 = __shfl(sidx, jj, 64);
                int a1 = __shfl(sidx, jj + 1, 64);
                int a2 = __shfl(sidx, jj + 2, 64);
                int a3 = __shfl(sidx, jj + 3, 64);
                s0 += x[a0 * 64 + lane];
                s1 += x[a1 * 64 + lane];
                s2 += x[a2 * 64 + lane];
                s3 += x[a3 * 64 + lane];
            }
            for (; jj < n; ++jj) {
                int a = __shfl(sidx, jj, 64);
                s0 += x[a * 64 + lane];
            }
        }
        float sum = (s0 + s1) + (s2 + s3);
#pragma unroll
        for (int off = 32; off > 0; off >>= 1) sumtau += __shfl_down(sumtau, off, 64);
        sumtau = __shfl(sumtau, 0, 64);

        float inv = 1.f / fmaxf((float)d, 1.f);
        float mean = sum * inv;
        float mtau = sumtau * inv;
        float xi = x[node * 64 + lane];
        float ti = tau[node];

        float acc = bl + mtau * wl_tau + ti * wr_tau;
#pragma unroll 8
        for (int k = 0; k < 64; ++k) {
            float mk = __shfl(mean, k, 64);
            float xk = __shfl(xi, k, 64);
            acc = fmaf(mk, sWl[k * 64 + lane], acc);
            acc = fmaf(xk, sWr[k * 64 + lane], acc);
        }
        h1[node * 64 + lane] = fmaxf(acc, 0.f);
    }
}

// Layer 2 + fc head: out = relu(mean(h1[nbrs]) @ W2l + h1 @ W2r + b2l) @ Wfc + bfc
__global__ __launch_bounds__(LAYER_BLOCK) void k_layer2(
    const float* __restrict__ h1,
    const int* __restrict__ rowptr, const int* __restrict__ deg,
    const int* __restrict__ colidx,
    const float* __restrict__ W2l, const float* __restrict__ b2l,
    const float* __restrict__ W2r, const float* __restrict__ Wfc,
    const float* __restrict__ bfc, float* __restrict__ out, int N) {
    __shared__ float sW[64 * 64 * 2 + 64];
    for (int i = threadIdx.x; i < 64 * 64 * 2; i += LAYER_BLOCK)
        sW[i] = (i < 64 * 64) ? W2l[i] : W2r[i - 64 * 64];
    if (threadIdx.x < 64) sW[64 * 64 * 2 + threadIdx.x] = Wfc[threadIdx.x];
    __syncthreads();
    const float* sWl = sW;
    const float* sWr = sW + 64 * 64;
    const float* sWfc = sW + 64 * 64 * 2;

    int lane = threadIdx.x & 63;
    int wave = blockIdx.x * WAVES_PER_BLOCK + (threadIdx.x >> 6);
    int nwaves = gridDim.x * WAVES_PER_BLOCK;

    float bl = b2l[lane];
    float wfc = sWfc[lane];
    float b0 = bfc[0];

    for (int node = wave; node < N; node += nwaves) {
        int start = rowptr[node];
        int d = deg[node];
        float s0 = 0.f, s1 = 0.f, s2 = 0.f, s3 = 0.f;
        for (int base = 0; base < d; base += 64) {
            int n = d - base;
            if (n > 64) n = 64;
            int sidx = 0;
            if (lane < n) sidx = colidx[start + base + lane];
            int jj = 0;
            for (; jj + 4 <= n; jj += 4) {
                int a0 = __shfl(sidx, jj, 64);
                int a1 = __shfl(sidx, jj + 1, 64);
                int a2 = __shfl(sidx, jj + 2, 64);
                int a3 = __shfl(sidx, jj + 3, 64);
                s0 += h1[a0 * 64 + lane];
                s1 += h1[a1 * 64 + lane];
                s2 += h1[a2 * 64 + lane];
                s3 += h1[a3 * 64 + lane];
            }
            for (; jj < n; ++jj) {
                int a = __shfl(sidx, jj, 64);
                s0 += h1[a * 64 + lane];
            }
        }
        float sum = (s0 + s1) + (s2 + s3);
        float inv = 1.f / fmaxf((float)d, 1.f);
        float mean = sum * inv;
        float hi = h1[node * 64 + lane];

        float acc = bl;
#pragma unroll 8
        for (int k = 0; k < 64; ++k) {
            float mk = __shfl(mean, k, 64);
            float hk = __shfl(hi, k, 64);
            acc = fmaf(mk, sWl[k * 64 + lane], acc);
            acc = fmaf(hk, sWr[k * 64 + lane], acc);
        }
        float h2 = fmaxf(acc, 0.f);
        float p = h2 * wfc;
#pragma unroll
        for (int off = 32; off > 0; off >>= 1) p += __shfl_down(p, off, 64);
        if (lane == 0) out[node] = p + b0;
    }
}

extern "C" void kernel_launch(void* const* d_in, const int* in_sizes, int n_in,
                              void* d_out, int out_size, void* d_ws, size_t ws_size,
                              hipStream_t stream) {
    const float* x   = (const float*)d_in[0];
    const int*   ei  = (const int*)d_in[1];
    const float* tau = (const float*)d_in[2];
    const float* W1l = (const float*)d_in[3];
    const float* b1l = (const float*)d_in[4];
    const float* W1r = (const float*)d_in[5];
    const float* W2l = (const float*)d_in[6];
    const float* b2l = (const float*)d_in[7];
    const float* W2r = (const float*)d_in[8];
    const float* Wfc = (const float*)d_in[9];
    const float* bfc = (const float*)d_in[10];
    float* out = (float*)d_out;

    const int N = in_sizes[0] / 64;   // 100000
    const int E = in_sizes[1] / 2;    // 3200000
    const int* src = ei;
    const int* dst = ei + E;

    // workspace carve-out (256B aligned): deg, rowptr, cursor, bsum, colidx, h1
    char* w = (char*)d_ws;
    auto take = [&](size_t b) { char* p = w; w += (b + 255) & ~(size_t)255; return p; };
    int*   deg    = (int*)take((size_t)N * 4);
    int*   rowptr = (int*)take((size_t)N * 4);
    int*   cursor = (int*)take((size_t)N * 4);
    int*   bsum   = (int*)take(512 * 4);
    int*   colidx = (int*)take((size_t)E * 4);
    float* h1     = (float*)take((size_t)N * 64 * 4);

    hipMemsetAsync(deg, 0, (size_t)N * 4, stream);

    int nbE = (E + 255) / 256;
    int nbN = (N + 255) / 256;  // 391 <= 512 (required by k_scanb)

    k_count<<<nbE, 256, 0, stream>>>(dst, deg, E);
    k_blockscan<<<nbN, 256, 0, stream>>>(deg, rowptr, bsum, N);
    k_scanb<<<1, 512, 0, stream>>>(bsum, nbN);
    k_finalize<<<nbN, 256, 0, stream>>>(rowptr, cursor, bsum, N);
    k_fill<<<nbE, 256, 0, stream>>>(src, dst, cursor, colidx, E);
    k_layer1<<<LAYER_GRID, LAYER_BLOCK, 0, stream>>>(x, tau, rowptr, deg, colidx,
                                                     W1l, b1l, W1r, h1, N);
    k_layer2<<<LAYER_GRID, LAYER_BLOCK, 0, stream>>>(h1, rowptr, deg, colidx,
                                                     W2l, b2l, W2r, Wfc, bfc, out, N);
}

// Round 2
// 653.561 us; speedup vs baseline: 1.5125x; 1.5125x over previous
//
#include <hip/hip_runtime.h>
#include <hip/hip_bf16.h>

// GQNN: 2-layer GraphSAGE (mean aggr) + fc head. N=100k, E=3.2M, d=64/65.
// R2: CSR build via two-level counting sort (bucket = dst>>7, 128 nodes/bucket)
// to kill the 15x write amplification of random 4B scatter (R1: k_fill 275us,
// WRITE_SIZE 194MB for a 12.8MB colidx). All build writes are now block-local
// contiguous streams. Layer kernels unchanged from R1 (known-correct).

#define WAVES_PER_BLOCK 16
#define LAYER_BLOCK (WAVES_PER_BLOCK * 64)
#define LAYER_GRID 512

#define BSH 7                    // bucket shift: 128 nodes per bucket
#define NBKT 782                 // ceil(100000 / 128)
#define NBLK 256                 // binning blocks

// Pass A: per-block LDS histogram over buckets -> histT[k*NBLK + b]
__global__ __launch_bounds__(256) void k_hist(const int* __restrict__ dst,
                                              int* __restrict__ histT, int E) {
    __shared__ int h[NBKT];
    for (int i = threadIdx.x; i < NBKT; i += 256) h[i] = 0;
    __syncthreads();
    int per = (E + NBLK - 1) / NBLK;
    int lo = blockIdx.x * per;
    int hi = lo + per; if (hi > E) hi = E;
    for (int e = lo + threadIdx.x; e < hi; e += 256)
        atomicAdd(&h[dst[e] >> BSH], 1);
    __syncthreads();
    for (int k = threadIdx.x; k < NBKT; k += 256)
        histT[k * NBLK + blockIdx.x] = h[k];
}

// Scan over blocks within each bucket (one workgroup per bucket).
__global__ __launch_bounds__(NBLK) void k_scanblk(int* __restrict__ histT,
                                                  int* __restrict__ btot) {
    __shared__ int s[NBLK];
    int k = blockIdx.x, t = threadIdx.x;
    int v = histT[k * NBLK + t];
    s[t] = v;
    __syncthreads();
    for (int off = 1; off < NBLK; off <<= 1) {
        int u = (t >= off) ? s[t - off] : 0;
        __syncthreads();
        s[t] += u;
        __syncthreads();
    }
    histT[k * NBLK + t] = s[t] - v;   // exclusive prefix within bucket
    if (t == NBLK - 1) btot[k] = s[t];
}

// Scan bucket totals (NBKT=782 <= 1024) -> bstart[k], sentinel bstart[NBKT]=E.
__global__ __launch_bounds__(1024) void k_scanbkt(const int* __restrict__ btot,
                                                  int* __restrict__ bstart) {
    __shared__ int s[1024];
    int t = threadIdx.x;
    int v = (t < NBKT) ? btot[t] : 0;
    s[t] = v;
    __syncthreads();
    for (int off = 1; off < 1024; off <<= 1) {
        int u = (t >= off) ? s[t - off] : 0;
        __syncthreads();
        s[t] += u;
        __syncthreads();
    }
    if (t < NBKT) bstart[t] = s[t] - v;
    if (t == NBKT - 1) bstart[NBKT] = s[t];  // total = E
}

// Pass B: scatter packed (src<<7 | dst&127) into bucket-sorted order.
__global__ __launch_bounds__(256) void k_scatter(const int* __restrict__ src,
                                                 const int* __restrict__ dst,
                                                 const int* __restrict__ histT,
                                                 const int* __restrict__ bstart,
                                                 int* __restrict__ binned, int E) {
    __shared__ int cur[NBKT];
    int b = blockIdx.x;
    for (int k = threadIdx.x; k < NBKT; k += 256)
        cur[k] = bstart[k] + histT[k * NBLK + b];
    __syncthreads();
    int per = (E + NBLK - 1) / NBLK;
    int lo = b * per;
    int hi = lo + per; if (hi > E) hi = E;
    for (int e = lo + threadIdx.x; e < hi; e += 256) {
        int d = dst[e], s = src[e];
        int pos = atomicAdd(&cur[d >> BSH], 1);
        binned[pos] = (s << BSH) | (d & ((1 << BSH) - 1));
    }
}

// Pass C: one block per bucket: local CSR (count/scan/fill) over 128 nodes.
__global__ __launch_bounds__(256) void k_bucket(const int* __restrict__ binned,
                                                const int* __restrict__ bstart,
                                                int* __restrict__ rowptr,
                                                int* __restrict__ deg,
                                                int* __restrict__ colidx, int N) {
    __shared__ int cnt[128], sc[128], cur[128];
    int k = blockIdx.x, t = threadIdx.x;
    int lo = bstart[k], hi = bstart[k + 1];
    if (t < 128) cnt[t] = 0;
    __syncthreads();
    for (int e = lo + t; e < hi; e += 256)
        atomicAdd(&cnt[binned[e] & 127], 1);
    __syncthreads();
    if (t < 128) sc[t] = cnt[t];
    __syncthreads();
    for (int off = 1; off < 128; off <<= 1) {
        int u = 0;
        if (t < 128 && t >= off) u = sc[t - off];
        __syncthreads();
        if (t < 128) sc[t] += u;
        __syncthreads();
    }
    if (t < 128) {
        int abs0 = lo + (sc[t] - cnt[t]);
        cur[t] = abs0;
        int gnode = (k << BSH) + t;
        if (gnode < N) { rowptr[gnode] = abs0; deg[gnode] = cnt[t]; }
    }
    __syncthreads();
    for (int e = lo + t; e < hi; e += 256) {
        int p = binned[e];
        int pos = atomicAdd(&cur[p & 127], 1);
        colidx[pos] = p >> BSH;
    }
}

// Layer 1: h1 = relu(mean([x|tau][nbrs]) @ W1l + [x|tau] @ W1r + b1l)
__global__ __launch_bounds__(LAYER_BLOCK) void k_layer1(
    const float* __restrict__ x, const float* __restrict__ tau,
    const int* __restrict__ rowptr, const int* __restrict__ deg,
    const int* __restrict__ colidx,
    const float* __restrict__ W1l, const float* __restrict__ b1l,
    const float* __restrict__ W1r, float* __restrict__ h1, int N) {
    __shared__ float sW[65 * 64 * 2];
    for (int i = threadIdx.x; i < 65 * 64 * 2; i += LAYER_BLOCK)
        sW[i] = (i < 65 * 64) ? W1l[i] : W1r[i - 65 * 64];
    __syncthreads();
    const float* sWl = sW;
    const float* sWr = sW + 65 * 64;

    int lane = threadIdx.x & 63;
    int wave = blockIdx.x * WAVES_PER_BLOCK + (threadIdx.x >> 6);
    int nwaves = gridDim.x * WAVES_PER_BLOCK;

    float bl = b1l[lane];
    float wl_tau = sWl[64 * 64 + lane];
    float wr_tau = sWr[64 * 64 + lane];

    for (int node = wave; node < N; node += nwaves) {
        int start = rowptr[node];
        int d = deg[node];
        float s0 = 0.f, s1 = 0.f, s2 = 0.f, s3 = 0.f, sumtau = 0.f;
        for (int base = 0; base < d; base += 64) {
            int n = d - base;
            if (n > 64) n = 64;
            int sidx = 0;
            if (lane < n) {
                sidx = colidx[start + base + lane];
                sumtau += tau[sidx];
            }
            int jj = 0;
            for (; jj + 4 <= n; jj += 4) {
                int a0 = __shfl(sidx, jj, 64);
                int a1 = __shfl(sidx, jj + 1, 64);
                int a2 = __shfl(sidx, jj + 2, 64);
                int a3 = __shfl(sidx, jj + 3, 64);
                s0 += x[a0 * 64 + lane];
                s1 += x[a1 * 64 + lane];
                s2 += x[a2 * 64 + lane];
                s3 += x[a3 * 64 + lane];
            }
            for (; jj < n; ++jj) {
                int a = __shfl(sidx, jj, 64);
                s0 += x[a * 64 + lane];
            }
        }
        float sum = (s0 + s1) + (s2 + s3);
#pragma unroll
        for (int off = 32; off > 0; off >>= 1) sumtau += __shfl_down(sumtau, off, 64);
        sumtau = __shfl(sumtau, 0, 64);

        float inv = 1.f / fmaxf((float)d, 1.f);
        float mean = sum * inv;
        float mtau = sumtau * inv;
        float xi = x[node * 64 + lane];
        float ti = tau[node];

        float acc = bl + mtau * wl_tau + ti * wr_tau;
#pragma unroll 8
        for (int k = 0; k < 64; ++k) {
            float mk = __shfl(mean, k, 64);
            float xk = __shfl(xi, k, 64);
            acc = fmaf(mk, sWl[k * 64 + lane], acc);
            acc = fmaf(xk, sWr[k * 64 + lane], acc);
        }
        h1[node * 64 + lane] = fmaxf(acc, 0.f);
    }
}

// Layer 2 + fc head
__global__ __launch_bounds__(LAYER_BLOCK) void k_layer2(
    const float* __restrict__ h1,
    const int* __restrict__ rowptr, const int* __restrict__ deg,
    const int* __restrict__ colidx,
    const float* __restrict__ W2l, const float* __restrict__ b2l,
    const float* __restrict__ W2r, const float* __restrict__ Wfc,
    const float* __restrict__ bfc, float* __restrict__ out, int N) {
    __shared__ float sW[64 * 64 * 2 + 64];
    for (int i = threadIdx.x; i < 64 * 64 * 2; i += LAYER_BLOCK)
        sW[i] = (i < 64 * 64) ? W2l[i] : W2r[i - 64 * 64];
    if (threadIdx.x < 64) sW[64 * 64 * 2 + threadIdx.x] = Wfc[threadIdx.x];
    __syncthreads();
    const float* sWl = sW;
    const float* sWr = sW + 64 * 64;
    const float* sWfc = sW + 64 * 64 * 2;

    int lane = threadIdx.x & 63;
    int wave = blockIdx.x * WAVES_PER_BLOCK + (threadIdx.x >> 6);
    int nwaves = gridDim.x * WAVES_PER_BLOCK;

    float bl = b2l[lane];
    float wfc = sWfc[lane];
    float b0 = bfc[0];

    for (int node = wave; node < N; node += nwaves) {
        int start = rowptr[node];
        int d = deg[node];
        float s0 = 0.f, s1 = 0.f, s2 = 0.f, s3 = 0.f;
        for (int base = 0; base < d; base += 64) {
            int n = d - base;
            if (n > 64) n = 64;
            int sidx = 0;
            if (lane < n) sidx = colidx[start + base + lane];
            int jj = 0;
            for (; jj + 4 <= n; jj += 4) {
                int a0 = __shfl(sidx, jj, 64);
                int a1 = __shfl(sidx, jj + 1, 64);
                int a2 = __shfl(sidx, jj + 2, 64);
                int a3 = __shfl(sidx, jj + 3, 64);
                s0 += h1[a0 * 64 + lane];
                s1 += h1[a1 * 64 + lane];
                s2 += h1[a2 * 64 + lane];
                s3 += h1[a3 * 64 + lane];
            }
            for (; jj < n; ++jj) {
                int a = __shfl(sidx, jj, 64);
                s0 += h1[a * 64 + lane];
            }
        }
        float sum = (s0 + s1) + (s2 + s3);
        float inv = 1.f / fmaxf((float)d, 1.f);
        float mean = sum * inv;
        float hi = h1[node * 64 + lane];

        float acc = bl;
#pragma unroll 8
        for (int k = 0; k < 64; ++k) {
            float mk = __shfl(mean, k, 64);
            float hk = __shfl(hi, k, 64);
            acc = fmaf(mk, sWl[k * 64 + lane], acc);
            acc = fmaf(hk, sWr[k * 64 + lane], acc);
        }
        float h2 = fmaxf(acc, 0.f);
        float p = h2 * wfc;
#pragma unroll
        for (int off = 32; off > 0; off >>= 1) p += __shfl_down(p, off, 64);
        if (lane == 0) out[node] = p + b0;
    }
}

extern "C" void kernel_launch(void* const* d_in, const int* in_sizes, int n_in,
                              void* d_out, int out_size, void* d_ws, size_t ws_size,
                              hipStream_t stream) {
    const float* x   = (const float*)d_in[0];
    const int*   ei  = (const int*)d_in[1];
    const float* tau = (const float*)d_in[2];
    const float* W1l = (const float*)d_in[3];
    const float* b1l = (const float*)d_in[4];
    const float* W1r = (const float*)d_in[5];
    const float* W2l = (const float*)d_in[6];
    const float* b2l = (const float*)d_in[7];
    const float* W2r = (const float*)d_in[8];
    const float* Wfc = (const float*)d_in[9];
    const float* bfc = (const float*)d_in[10];
    float* out = (float*)d_out;

    const int N = in_sizes[0] / 64;   // 100000
    const int E = in_sizes[1] / 2;    // 3200000
    const int* src = ei;
    const int* dst = ei + E;

    char* w = (char*)d_ws;
    auto take = [&](size_t b) { char* p = w; w += (b + 255) & ~(size_t)255; return p; };
    int*   histT  = (int*)take((size_t)NBKT * NBLK * 4);   // 800 KB
    int*   btot   = (int*)take((size_t)NBKT * 4);
    int*   bstart = (int*)take((size_t)(NBKT + 1) * 4);
    int*   binned = (int*)take((size_t)E * 4);             // 12.8 MB
    int*   rowptr = (int*)take((size_t)N * 4);
    int*   deg    = (int*)take((size_t)N * 4);
    int*   colidx = (int*)take((size_t)E * 4);             // 12.8 MB
    float* h1     = (float*)take((size_t)N * 64 * 4);      // 25.6 MB

    k_hist   <<<NBLK, 256, 0, stream>>>(dst, histT, E);
    k_scanblk<<<NBKT, NBLK, 0, stream>>>(histT, btot);
    k_scanbkt<<<1, 1024, 0, stream>>>(btot, bstart);
    k_scatter<<<NBLK, 256, 0, stream>>>(src, dst, histT, bstart, binned, E);
    k_bucket <<<NBKT, 256, 0, stream>>>(binned, bstart, rowptr, deg, colidx, N);
    k_layer1 <<<LAYER_GRID, LAYER_BLOCK, 0, stream>>>(x, tau, rowptr, deg, colidx,
                                                      W1l, b1l, W1r, h1, N);
    k_layer2 <<<LAYER_GRID, LAYER_BLOCK, 0, stream>>>(h1, rowptr, deg, colidx,
                                                      W2l, b2l, W2r, Wfc, bfc, out, N);
}